// Round 1
// baseline (266.691 us; speedup 1.0000x reference)
//
#include <hip/hip_runtime.h>
#include <math.h>

#define HIDDEN 256
#define BATCH 8192
#define NEGS 16
#define NSCORES (BATCH + BATCH * NEGS)  // 139264

// One wave (64 lanes) per score. Lane L owns i = 4L..4L+3.
// inner = sum_i sum_k h[i] * r[k] * t[(i+k) % 256]
//       = sum_c h[4L+c] * X_c,  X_c = sum_k r[k] * t[(4L+c+k) % 256]
// t staged duplicated in LDS (512 floats) -> no modulo, aligned float4 windows.
// r loaded via wave-uniform scalar loads (SGPR operand to FMA).
__global__ __launch_bounds__(256, 8) void score_kernel(
    const int* __restrict__ pos_h, const int* __restrict__ pos_t, const int* __restrict__ pos_r,
    const int* __restrict__ neg_h, const int* __restrict__ neg_t, const int* __restrict__ neg_r,
    const float* __restrict__ ent, const float* __restrict__ rel,
    float* __restrict__ scores)
{
    __shared__ __align__(16) float ldsT[4][512];
    const int wave = threadIdx.x >> 6;
    const int lane = threadIdx.x & 63;
    const int s = blockIdx.x * 4 + wave;

    int hi, ti, ri;
    if (s < BATCH) {
        hi = pos_h[s]; ti = pos_t[s]; ri = pos_r[s];
    } else {
        const int j = s - BATCH;
        hi = neg_h[j]; ti = neg_t[j]; ri = neg_r[j];
    }
    // indices are wave-uniform: make it explicit so addresses go scalar
    hi = __builtin_amdgcn_readfirstlane(hi);
    ti = __builtin_amdgcn_readfirstlane(ti);
    ri = __builtin_amdgcn_readfirstlane(ri);

    const float* __restrict__ hrow = ent + (long)hi * HIDDEN;
    const float* __restrict__ trow = ent + (long)ti * HIDDEN;
    const float* __restrict__ rrow = rel + (long)ri * HIDDEN;

    const float4 hv = *(const float4*)(hrow + 4 * lane);
    const float4 tv = *(const float4*)(trow + 4 * lane);

    // stage t twice (rotation without modulo)
    *(float4*)(&ldsT[wave][4 * lane])       = tv;
    *(float4*)(&ldsT[wave][256 + 4 * lane]) = tv;

    // per-lane partial of ||r||^2 (normalization commutes: divide at the end)
    const float4 rv = *(const float4*)(rrow + 4 * lane);
    float rn2 = rv.x * rv.x + rv.y * rv.y + rv.z * rv.z + rv.w * rv.w;

    __syncthreads();

    float X0 = 0.f, X1 = 0.f, X2 = 0.f, X3 = 0.f;
    const float* __restrict__ tl = &ldsT[wave][4 * lane];

    for (int k0 = 0; k0 < HIDDEN; k0 += 16) {
        float tw[20] __attribute__((aligned(16)));
        #pragma unroll
        for (int q = 0; q < 5; ++q)
            *(float4*)(tw + 4 * q) = *(const float4*)(tl + k0 + 4 * q);
        #pragma unroll
        for (int kk = 0; kk < 16; ++kk) {
            const float rk = rrow[k0 + kk];   // uniform -> s_load, SGPR src
            X0 = fmaf(rk, tw[kk],     X0);
            X1 = fmaf(rk, tw[kk + 1], X1);
            X2 = fmaf(rk, tw[kk + 2], X2);
            X3 = fmaf(rk, tw[kk + 3], X3);
        }
    }

    float lane_sum = hv.x * X0;
    lane_sum = fmaf(hv.y, X1, lane_sum);
    lane_sum = fmaf(hv.z, X2, lane_sum);
    lane_sum = fmaf(hv.w, X3, lane_sum);

    // wave reduction of (lane_sum, rn2)
    #pragma unroll
    for (int m = 32; m >= 1; m >>= 1) {
        lane_sum += __shfl_xor(lane_sum, m);
        rn2      += __shfl_xor(rn2, m);
    }

    if (lane == 0) {
        const float inner = lane_sum * rsqrtf(fmaxf(rn2, 1e-12f));
        const float sc = -1.0f / (1.0f + __expf(-inner));
        scores[s] = sc;
    }
}

// Deterministic single-block loss reduction (no atomics, fully overwrites out).
__global__ __launch_bounds__(1024) void loss_kernel(
    const float* __restrict__ scores, float* __restrict__ out)
{
    __shared__ float red[16];
    float sum = 0.f;
    for (int b = threadIdx.x; b < BATCH; b += 1024) {
        const float p = scores[b];
        const float* __restrict__ np = scores + BATCH + b * NEGS;
        float n = 0.f;
        #pragma unroll
        for (int j = 0; j < NEGS; ++j) n += np[j];
        n *= (1.0f / NEGS);
        sum += fmaxf(p - n + 1.0f, 0.0f);
    }
    #pragma unroll
    for (int m = 32; m >= 1; m >>= 1) sum += __shfl_xor(sum, m);
    const int wave = threadIdx.x >> 6;
    const int lane = threadIdx.x & 63;
    if (lane == 0) red[wave] = sum;
    __syncthreads();
    if (threadIdx.x < 16) {
        float v = red[threadIdx.x];
        #pragma unroll
        for (int m = 8; m >= 1; m >>= 1) v += __shfl_xor(v, m, 16);
        if (threadIdx.x == 0) out[0] = v;
    }
}

extern "C" void kernel_launch(void* const* d_in, const int* in_sizes, int n_in,
                              void* d_out, int out_size, void* d_ws, size_t ws_size,
                              hipStream_t stream) {
    (void)in_sizes; (void)n_in; (void)out_size; (void)ws_size;
    const int* pos_h = (const int*)d_in[0];
    const int* pos_t = (const int*)d_in[1];
    const int* pos_r = (const int*)d_in[2];
    const int* neg_h = (const int*)d_in[3];
    const int* neg_t = (const int*)d_in[4];
    const int* neg_r = (const int*)d_in[5];
    const float* ent = (const float*)d_in[6];
    const float* rel = (const float*)d_in[7];

    float* scores = (float*)d_ws;          // 139264 floats = 544 KB
    float* out = (float*)d_out;

    score_kernel<<<dim3(NSCORES / 4), dim3(256), 0, stream>>>(
        pos_h, pos_t, pos_r, neg_h, neg_t, neg_r, ent, rel, scores);
    loss_kernel<<<dim3(1), dim3(1024), 0, stream>>>(scores, out);
}

// Round 3
// 169.140 us; speedup vs baseline: 1.5768x; 1.5768x over previous
//
#include <hip/hip_runtime.h>
#include <math.h>

#define HIDDEN 256
#define BATCH 8192
#define NEGS 16
#define NSCORES (BATCH + BATCH * NEGS)  // 139264

typedef _Float16 h2 __attribute__((ext_vector_type(2)));
typedef unsigned int uint32;

__device__ __forceinline__ float fdot2f(h2 a, h2 b, float c) {
#if __has_builtin(__builtin_amdgcn_fdot2)
    return __builtin_amdgcn_fdot2(a, b, c, false);
#else
    return c + (float)a.x * (float)b.x + (float)a.y * (float)b.y;
#endif
}

__device__ __forceinline__ h2 pk16(float a, float b) {
#if __has_builtin(__builtin_amdgcn_cvt_pkrtz)
    auto p = __builtin_amdgcn_cvt_pkrtz(a, b);  // __fp16 ext_vector(2)
    h2 r;
    __builtin_memcpy(&r, &p, sizeof(r));        // same bits, clang type fix
    return r;
#else
    h2 r; r.x = (_Float16)a; r.y = (_Float16)b; return r;
#endif
}

__device__ __forceinline__ uint32 alignb(uint32 hi, uint32 lo) {
#if __has_builtin(__builtin_amdgcn_alignbit)
    return __builtin_amdgcn_alignbit(hi, lo, 16);
#else
    return (lo >> 16) | (hi << 16);
#endif
}

// 16 lanes per score, 4 scores per wave, 4 waves (16 scores) per block.
// inner = sum_c h[c] * X[c],  X[c] = sum_k r[k] * t[(c + k) % 256]
// Lane L of a group owns c = 16L .. 16L+15 (h fp32 in regs).
// t staged duplicated in LDS as f16 (512 halves); r staged as f16 (256 halves).
// k-loop in blocks of 32; dot2 pairs along k; odd-c windows built with alignbit.
__global__ __launch_bounds__(256) void score_kernel(
    const int* __restrict__ pos_h, const int* __restrict__ pos_t, const int* __restrict__ pos_r,
    const int* __restrict__ neg_h, const int* __restrict__ neg_t, const int* __restrict__ neg_r,
    const float* __restrict__ ent, const float* __restrict__ rel,
    float* __restrict__ scores)
{
    __shared__ __align__(16) _Float16 T[16][512];
    __shared__ __align__(16) _Float16 R[16][256];

    const int tid = threadIdx.x;
    const int wave = tid >> 6;
    const int lane = tid & 63;
    const int g = lane >> 4;     // score group within wave
    const int L = lane & 15;     // lane within group
    const int sl = wave * 4 + g; // score slot within block (0..15)
    const int s = blockIdx.x * 16 + sl;

    int hi, ti, ri;
    if (s < BATCH) {
        hi = pos_h[s]; ti = pos_t[s]; ri = pos_r[s];
    } else {
        const int j = s - BATCH;
        hi = neg_h[j]; ti = neg_t[j]; ri = neg_r[j];
    }

    const float* __restrict__ hrow = ent + (long)hi * HIDDEN + 16 * L;
    const float* __restrict__ trow = ent + (long)ti * HIDDEN + 16 * L;
    const float* __restrict__ rrow = rel + (long)ri * HIDDEN + 16 * L;

    float tv[16], rv[16], hv[16];
    #pragma unroll
    for (int q = 0; q < 4; ++q) {
        ((float4*)tv)[q] = ((const float4*)trow)[q];
        ((float4*)rv)[q] = ((const float4*)rrow)[q];
        ((float4*)hv)[q] = ((const float4*)hrow)[q];
    }

    // stage t (duplicated) as f16
    uint4 tcu[2];
    h2* tc = (h2*)tcu;
    #pragma unroll
    for (int j = 0; j < 8; ++j) tc[j] = pk16(tv[2 * j], tv[2 * j + 1]);
    *(uint4*)&T[sl][16 * L]           = tcu[0];
    *(uint4*)&T[sl][16 * L + 8]       = tcu[1];
    *(uint4*)&T[sl][256 + 16 * L]     = tcu[0];
    *(uint4*)&T[sl][256 + 16 * L + 8] = tcu[1];

    // stage r as f16 + ||r||^2 partial (fp32)
    uint4 rcu[2];
    h2* rc = (h2*)rcu;
    #pragma unroll
    for (int j = 0; j < 8; ++j) rc[j] = pk16(rv[2 * j], rv[2 * j + 1]);
    *(uint4*)&R[sl][16 * L]     = rcu[0];
    *(uint4*)&R[sl][16 * L + 8] = rcu[1];
    float rn2 = 0.f;
    #pragma unroll
    for (int i = 0; i < 16; ++i) rn2 = fmaf(rv[i], rv[i], rn2);

    __syncthreads();

    float X[16];
    #pragma unroll
    for (int i = 0; i < 16; ++i) X[i] = 0.f;

    for (int kb = 0; kb < 8; ++kb) {
        const int base = 16 * L + 32 * kb;
        uint4 tb[6];
        #pragma unroll
        for (int q = 0; q < 6; ++q) tb[q] = *(const uint4*)&T[sl][base + 8 * q];
        uint4 rb[4];
        #pragma unroll
        for (int q = 0; q < 4; ++q) rb[q] = *(const uint4*)&R[sl][32 * kb + 8 * q];

        const uint32* tu = (const uint32*)tb;  // 24 words = 48 halves: t[base .. base+47]
        const h2* te = (const h2*)tb;          // even-aligned pairs
        const h2* r2 = (const h2*)rb;          // 16 pairs: r[32kb .. 32kb+31]

        uint32 wo_u[23];                       // odd-aligned pairs (t[2j+1], t[2j+2])
        #pragma unroll
        for (int j = 0; j < 23; ++j) wo_u[j] = alignb(tu[j + 1], tu[j]);
        const h2* wo = (const h2*)wo_u;

        #pragma unroll
        for (int m = 0; m < 16; ++m) {
            #pragma unroll
            for (int cc = 0; cc < 8; ++cc) {
                X[2 * cc]     = fdot2f(te[cc + m], r2[m], X[2 * cc]);
                X[2 * cc + 1] = fdot2f(wo[cc + m], r2[m], X[2 * cc + 1]);
            }
        }
    }

    float lane_sum = 0.f;
    #pragma unroll
    for (int i = 0; i < 16; ++i) lane_sum = fmaf(hv[i], X[i], lane_sum);

    // reduce (lane_sum, rn2) over the 16-lane group
    #pragma unroll
    for (int m = 1; m <= 8; m <<= 1) {
        lane_sum += __shfl_xor(lane_sum, m);
        rn2      += __shfl_xor(rn2, m);
    }

    if (L == 0) {
        const float inner = lane_sum * rsqrtf(fmaxf(rn2, 1e-12f));
        scores[s] = -1.0f / (1.0f + __expf(-inner));
    }
}

// Deterministic single-block loss reduction (fully overwrites out[0]).
__global__ __launch_bounds__(1024) void loss_kernel(
    const float* __restrict__ scores, float* __restrict__ out)
{
    __shared__ float red[16];
    float sum = 0.f;
    for (int b = threadIdx.x; b < BATCH; b += 1024) {
        const float p = scores[b];
        const float* __restrict__ np = scores + BATCH + b * NEGS;
        float n = 0.f;
        #pragma unroll
        for (int j = 0; j < NEGS; ++j) n += np[j];
        n *= (1.0f / NEGS);
        sum += fmaxf(p - n + 1.0f, 0.0f);
    }
    #pragma unroll
    for (int m = 32; m >= 1; m >>= 1) sum += __shfl_xor(sum, m);
    const int wave = threadIdx.x >> 6;
    const int lane = threadIdx.x & 63;
    if (lane == 0) red[wave] = sum;
    __syncthreads();
    if (threadIdx.x < 16) {
        float v = red[threadIdx.x];
        #pragma unroll
        for (int m = 8; m >= 1; m >>= 1) v += __shfl_xor(v, m, 16);
        if (threadIdx.x == 0) out[0] = v;
    }
}

extern "C" void kernel_launch(void* const* d_in, const int* in_sizes, int n_in,
                              void* d_out, int out_size, void* d_ws, size_t ws_size,
                              hipStream_t stream) {
    (void)in_sizes; (void)n_in; (void)out_size; (void)ws_size;
    const int* pos_h = (const int*)d_in[0];
    const int* pos_t = (const int*)d_in[1];
    const int* pos_r = (const int*)d_in[2];
    const int* neg_h = (const int*)d_in[3];
    const int* neg_t = (const int*)d_in[4];
    const int* neg_r = (const int*)d_in[5];
    const float* ent = (const float*)d_in[6];
    const float* rel = (const float*)d_in[7];

    float* scores = (float*)d_ws;  // 139264 floats = 544 KB
    float* out = (float*)d_out;

    score_kernel<<<dim3(NSCORES / 16), dim3(256), 0, stream>>>(
        pos_h, pos_t, pos_r, neg_h, neg_t, neg_r, ent, rel, scores);
    loss_kernel<<<dim3(1), dim3(1024), 0, stream>>>(scores, out);
}

// Round 4
// 111.725 us; speedup vs baseline: 2.3870x; 1.5139x over previous
//
#include <hip/hip_runtime.h>
#include <math.h>

#define HIDDEN 256
#define BATCH 8192
#define NEGS 16
#define NSCORES (BATCH + BATCH * NEGS)  // 139264
#define PI2 6.28318530717958647692f

__device__ __forceinline__ float2 cmul(float2 a, float2 b) {
    return make_float2(fmaf(a.x, b.x, -a.y * b.y), fmaf(a.x, b.y, a.y * b.x));
}

// DIF radix-4 butterfly: inputs at positions {p, p+L/4, p+2L/4, p+3L/4};
// u_k = 4-pt DFT at freq k (twiddle W_L^{p*k} applied by caller).
__device__ __forceinline__ void bfly4(float2 a, float2 b, float2 c, float2 d,
                                      float2& u0, float2& u1, float2& u2, float2& u3) {
    float2 apc = make_float2(a.x + c.x, a.y + c.y);
    float2 amc = make_float2(a.x - c.x, a.y - c.y);
    float2 bpd = make_float2(b.x + d.x, b.y + d.y);
    float2 bmd = make_float2(b.x - d.x, b.y - d.y);
    u0 = make_float2(apc.x + bpd.x, apc.y + bpd.y);
    u2 = make_float2(apc.x - bpd.x, apc.y - bpd.y);
    u1 = make_float2(amc.x + bmd.y, amc.y - bmd.x);   // (a-c) - i(b-d)
    u3 = make_float2(amc.x - bmd.y, amc.y + bmd.x);   // (a-c) + i(b-d)
}

// Final DFT-4 across a quad of lanes (positions q = lane&3) via shfl_xor.
// Lane q ends with output bin-digit k''' = qmap[q] = {0,2,1,3}.
__device__ __forceinline__ float2 dft4_quad(float2 y, int q) {
    float2 p = make_float2(__shfl_xor(y.x, 2), __shfl_xor(y.y, 2));
    float2 v;
    if (q & 2) { v.x = p.x - y.x; v.y = p.y - y.y; }
    else       { v.x = y.x + p.x; v.y = y.y + p.y; }
    if (q == 3) { float t = v.x; v.x = v.y; v.y = -t; }  // multiply by -i
    float2 p2 = make_float2(__shfl_xor(v.x, 1), __shfl_xor(v.y, 1));
    float2 o;
    if (q & 1) { o.x = p2.x - v.x; o.y = p2.y - v.y; }
    else       { o.x = v.x + p2.x; o.y = v.y + p2.y; }
    return o;
}

// Pre-DFT the rel table. FrP[ri*256 + k2*64 + l] holds Fr[f(l,k2)] scaled:
//   .x = Re(Fr)/(2*256*||r||), .y = Im(Fr)/(4*256*||r||)
// f(l,k2) = (l>>4) + 4*((l>>2)&3) + 16*k2 + 64*qmap[l&3]  (FFT natural order)
__global__ __launch_bounds__(256) void rel_fft_kernel(
    const float* __restrict__ rel, float2* __restrict__ FrP)
{
    __shared__ float rrow[256];
    const int tid = threadIdx.x;
    const int ri = blockIdx.x;
    const int lane = tid & 63;
    rrow[tid] = rel[ri * 256 + tid];
    __syncthreads();

    float rn2 = 0.f;
    #pragma unroll
    for (int j = 0; j < 4; ++j) { float v = rrow[lane + 64 * j]; rn2 = fmaf(v, v, rn2); }
    #pragma unroll
    for (int m = 32; m >= 1; m >>= 1) rn2 += __shfl_xor(rn2, m);
    const float scale = rsqrtf(fmaxf(rn2, 1e-12f)) * (1.0f / 256.0f);

    const int l = tid & 63, k2 = tid >> 6;
    const int q = l & 3;
    const int qm = ((q & 1) << 1) | (q >> 1);
    const int f = (l >> 4) + 4 * ((l >> 2) & 3) + 16 * k2 + 64 * qm;

    // incremental DFT: Fr[f] = sum_k r[k] * e^{-2*pi*i*f*k/256}
    float ang = -PI2 * (float)f * (1.0f / 256.0f);
    float2 wstep = make_float2(__cosf(ang), __sinf(ang));
    float2 w = make_float2(1.f, 0.f);
    float re = 0.f, im = 0.f;
    #pragma unroll 4
    for (int k = 0; k < 256; ++k) {
        float rv = rrow[k];
        re = fmaf(rv, w.x, re);
        im = fmaf(rv, w.y, im);
        w = cmul(w, wstep);
    }
    FrP[ri * 256 + tid] = make_float2(re * (scale * 0.5f), im * (scale * 0.25f));
}

// One wave per score: FFT-256 of z = h + i*t, then
// inner = sum_f [ FrP.x * Im(Z[f]Z[-f]) + FrP.y * (|Z[-f]|^2 - |Z[f]|^2) ]
__global__ __launch_bounds__(256) void score_kernel(
    const int* __restrict__ pos_h, const int* __restrict__ pos_t, const int* __restrict__ pos_r,
    const int* __restrict__ neg_h, const int* __restrict__ neg_t, const int* __restrict__ neg_r,
    const float* __restrict__ ent, const float2* __restrict__ FrP,
    float* __restrict__ scores)
{
    __shared__ float2 tw[256];
    __shared__ float2 cf[4][288];   // per-wave scratch (padded layouts)

    const int tid = threadIdx.x, wave = tid >> 6, lane = tid & 63;
    {
        float ang = -PI2 * (float)tid * (1.0f / 256.0f);
        tw[tid] = make_float2(__cosf(ang), __sinf(ang));   // W^tid = e^{-2pi i tid/256}
    }

    const int s = blockIdx.x * 4 + wave;
    int hi, ti, ri;
    if (s < BATCH) { hi = pos_h[s]; ti = pos_t[s]; ri = pos_r[s]; }
    else { const int j = s - BATCH; hi = neg_h[j]; ti = neg_t[j]; ri = neg_r[j]; }

    const float* __restrict__ hrow = ent + (long)hi * HIDDEN;
    const float* __restrict__ trow = ent + (long)ti * HIDDEN;

    float2 z[4];
    #pragma unroll
    for (int j = 0; j < 4; ++j)
        z[j] = make_float2(hrow[lane + 64 * j], trow[lane + 64 * j]);

    __syncthreads();   // tw table ready
    float2* __restrict__ cfw = cf[wave];

    // ---- stage 1 (N=256): positions n' = lane, stride 64, in-lane
    {
        float2 u0, u1, u2, u3;
        bfly4(z[0], z[1], z[2], z[3], u0, u1, u2, u3);
        float2 w1 = tw[lane];
        float2 w2 = cmul(w1, w1);
        float2 w3 = cmul(w2, w1);
        // write series k0 at padded addr A1(x) = x + (x>>6), x = k0*64 + lane
        cfw[lane]            = u0;
        cfw[65 + lane]       = cmul(u1, w1);
        cfw[130 + lane]      = cmul(u2, w2);
        cfw[195 + lane]      = cmul(u3, w3);
    }

    // ---- stage 2 (N=64 per series): lane = (s16 = lane>>4, m = lane&15)
    {
        const int s16 = lane >> 4, m = lane & 15;
        const int b = s16 * 65 + m;     // A1-padded base
        float2 a0 = cfw[b], b0 = cfw[b + 16], c0 = cfw[b + 32], d0 = cfw[b + 48];
        float2 u0, u1, u2, u3;
        bfly4(a0, b0, c0, d0, u0, u1, u2, u3);
        float2 w1 = tw[4 * m];
        float2 w2 = cmul(w1, w1);
        float2 w3 = cmul(w2, w1);
        // write series16 sigma = s16*4+k1 at A2(x) = x + (x>>4), x = sigma*16 + m
        const int wb = s16 * 68 + m;    // (s16*4)*17 + m
        cfw[wb]          = u0;
        cfw[wb + 17]     = cmul(u1, w1);
        cfw[wb + 34]     = cmul(u2, w2);
        cfw[wb + 51]     = cmul(u3, w3);
    }

    // ---- stage 3 (N=16 per series): lane = (sigma = lane>>2, q = lane&3)
    float2 y0, y1, y2, y3;
    const int q = lane & 3;
    {
        const int sig = lane >> 2;
        const int b = sig * 17 + q;     // A2-padded base
        float2 a0 = cfw[b], b0 = cfw[b + 4], c0 = cfw[b + 8], d0 = cfw[b + 12];
        float2 u0, u1, u2, u3;
        bfly4(a0, b0, c0, d0, u0, u1, u2, u3);
        float2 w1 = tw[16 * q];
        float2 w2 = cmul(w1, w1);
        float2 w3 = cmul(w2, w1);
        y0 = u0; y1 = cmul(u1, w1); y2 = cmul(u2, w2); y3 = cmul(u3, w3);
    }

    // ---- stage 4: DFT-4 across quads via shuffles (slots k2 = 0..3)
    float2 o0 = dft4_quad(y0, q);
    float2 o1 = dft4_quad(y1, q);
    float2 o2 = dft4_quad(y2, q);
    float2 o3 = dft4_quad(y3, q);

    // bins: f = k0 + 4*k1 + 16*k2 + 64*qmap[q]
    const int k0 = lane >> 4, k1 = (lane >> 2) & 3;
    const int qm = ((q & 1) << 1) | (q >> 1);
    const int fbase = k0 + 4 * k1 + 64 * qm;

    // write Z at padded bin addr A3(x) = x + (x>>6)
    {
        const int f0 = fbase, f1 = fbase + 16, f2 = fbase + 32, f3 = fbase + 48;
        cfw[f0 + (f0 >> 6)] = o0;
        cfw[f1 + (f1 >> 6)] = o1;
        cfw[f2 + (f2 >> 6)] = o2;
        cfw[f3 + (f3 >> 6)] = o3;
    }

    // partner reads + rel contraction
    const float2* __restrict__ frbase = FrP + (long)ri * 256;
    float S = 0.f;
    float2 oz[4] = {o0, o1, o2, o3};
    #pragma unroll
    for (int k2 = 0; k2 < 4; ++k2) {
        const int f = fbase + 16 * k2;
        const int g = (256 - f) & 255;
        float2 A = oz[k2];
        float2 B = cfw[g + (g >> 6)];
        float2 fr = frbase[k2 * 64 + lane];
        const float imAB = A.x * B.y + A.y * B.x;
        const float dmag = (B.x * B.x + B.y * B.y) - (A.x * A.x + A.y * A.y);
        S = fmaf(fr.x, imAB, S);
        S = fmaf(fr.y, dmag, S);
    }

    #pragma unroll
    for (int m = 32; m >= 1; m >>= 1) S += __shfl_xor(S, m);

    if (lane == 0) {
        scores[s] = -1.0f / (1.0f + __expf(-S));
    }
}

// Deterministic single-block loss reduction (fully overwrites out[0]).
__global__ __launch_bounds__(1024) void loss_kernel(
    const float* __restrict__ scores, float* __restrict__ out)
{
    __shared__ float red[16];
    float sum = 0.f;
    for (int b = threadIdx.x; b < BATCH; b += 1024) {
        const float p = scores[b];
        const float* __restrict__ np = scores + BATCH + b * NEGS;
        float n = 0.f;
        #pragma unroll
        for (int j = 0; j < NEGS; ++j) n += np[j];
        n *= (1.0f / NEGS);
        sum += fmaxf(p - n + 1.0f, 0.0f);
    }
    #pragma unroll
    for (int m = 32; m >= 1; m >>= 1) sum += __shfl_xor(sum, m);
    const int wave = threadIdx.x >> 6;
    const int lane = threadIdx.x & 63;
    if (lane == 0) red[wave] = sum;
    __syncthreads();
    if (threadIdx.x < 16) {
        float v = red[threadIdx.x];
        #pragma unroll
        for (int m = 8; m >= 1; m >>= 1) v += __shfl_xor(v, m, 16);
        if (threadIdx.x == 0) out[0] = v;
    }
}

extern "C" void kernel_launch(void* const* d_in, const int* in_sizes, int n_in,
                              void* d_out, int out_size, void* d_ws, size_t ws_size,
                              hipStream_t stream) {
    (void)in_sizes; (void)n_in; (void)out_size; (void)ws_size;
    const int* pos_h = (const int*)d_in[0];
    const int* pos_t = (const int*)d_in[1];
    const int* pos_r = (const int*)d_in[2];
    const int* neg_h = (const int*)d_in[3];
    const int* neg_t = (const int*)d_in[4];
    const int* neg_r = (const int*)d_in[5];
    const float* ent = (const float*)d_in[6];
    const float* rel = (const float*)d_in[7];

    float2* FrP = (float2*)d_ws;                                    // 1000*256*8 = 2,048,000 B
    float* scores = (float*)((char*)d_ws + 1000 * 256 * sizeof(float2));
    float* out = (float*)d_out;

    rel_fft_kernel<<<dim3(1000), dim3(256), 0, stream>>>(rel, FrP);
    score_kernel<<<dim3(NSCORES / 4), dim3(256), 0, stream>>>(
        pos_h, pos_t, pos_r, neg_h, neg_t, neg_r, ent, FrP, scores);
    loss_kernel<<<dim3(1), dim3(1024), 0, stream>>>(scores, out);
}

// Round 5
// 109.743 us; speedup vs baseline: 2.4301x; 1.0181x over previous
//
#include <hip/hip_runtime.h>
#include <math.h>

#define HIDDEN 256
#define BATCH 8192
#define NEGS 16
#define NSCORES (BATCH + BATCH * NEGS)  // 139264
#define PI2 6.28318530717958647692f

__device__ __forceinline__ float2 cmul(float2 a, float2 b) {
    return make_float2(fmaf(a.x, b.x, -a.y * b.y), fmaf(a.x, b.y, a.y * b.x));
}

// DIF radix-4 butterfly
__device__ __forceinline__ void bfly4(float2 a, float2 b, float2 c, float2 d,
                                      float2& u0, float2& u1, float2& u2, float2& u3) {
    float2 apc = make_float2(a.x + c.x, a.y + c.y);
    float2 amc = make_float2(a.x - c.x, a.y - c.y);
    float2 bpd = make_float2(b.x + d.x, b.y + d.y);
    float2 bmd = make_float2(b.x - d.x, b.y - d.y);
    u0 = make_float2(apc.x + bpd.x, apc.y + bpd.y);
    u2 = make_float2(apc.x - bpd.x, apc.y - bpd.y);
    u1 = make_float2(amc.x + bmd.y, amc.y - bmd.x);   // (a-c) - i(b-d)
    u3 = make_float2(amc.x - bmd.y, amc.y + bmd.x);   // (a-c) + i(b-d)
}

// Final DFT-4 across a quad of lanes via shfl_xor; lane q ends with digit qmap[q]={0,2,1,3}.
__device__ __forceinline__ float2 dft4_quad(float2 y, int q) {
    float2 p = make_float2(__shfl_xor(y.x, 2), __shfl_xor(y.y, 2));
    float2 v;
    if (q & 2) { v.x = p.x - y.x; v.y = p.y - y.y; }
    else       { v.x = y.x + p.x; v.y = y.y + p.y; }
    if (q == 3) { float t = v.x; v.x = v.y; v.y = -t; }  // * -i
    float2 p2 = make_float2(__shfl_xor(v.x, 1), __shfl_xor(v.y, 1));
    float2 o;
    if (q & 1) { o.x = p2.x - v.x; o.y = p2.y - v.y; }
    else       { o.x = v.x + p2.x; o.y = v.y + p2.y; }
    return o;
}

// FFT-256 of z (element n = lane + 64*j) + contraction with preloaded fr[4].
// Returns S reduced across the wave. cfw is per-wave scratch (288 float2).
__device__ __forceinline__ float fft_contract(const float2 z[4], const float2 fr[4],
                                              float2* __restrict__ cfw,
                                              const float2* __restrict__ tw, int lane)
{
    // ---- stage 1 (N=256), in-lane over j, write at A1(x)=x+(x>>6)
    {
        float2 u0, u1, u2, u3;
        bfly4(z[0], z[1], z[2], z[3], u0, u1, u2, u3);
        float2 w1 = tw[lane];
        float2 w2 = cmul(w1, w1);
        float2 w3 = cmul(w2, w1);
        cfw[lane]       = u0;
        cfw[65 + lane]  = cmul(u1, w1);
        cfw[130 + lane] = cmul(u2, w2);
        cfw[195 + lane] = cmul(u3, w3);
    }
    // ---- stage 2 (N=64): lane = (s16, m); write at A2(x)=x+(x>>4)
    {
        const int s16 = lane >> 4, m = lane & 15;
        const int b = s16 * 65 + m;
        float2 a0 = cfw[b], b0 = cfw[b + 16], c0 = cfw[b + 32], d0 = cfw[b + 48];
        float2 u0, u1, u2, u3;
        bfly4(a0, b0, c0, d0, u0, u1, u2, u3);
        float2 w1 = tw[4 * m];
        float2 w2 = cmul(w1, w1);
        float2 w3 = cmul(w2, w1);
        const int wb = s16 * 68 + m;
        cfw[wb]      = u0;
        cfw[wb + 17] = cmul(u1, w1);
        cfw[wb + 34] = cmul(u2, w2);
        cfw[wb + 51] = cmul(u3, w3);
    }
    // ---- stage 3 (N=16): lane = (sigma, q)
    float2 y0, y1, y2, y3;
    const int q = lane & 3;
    {
        const int sig = lane >> 2;
        const int b = sig * 17 + q;
        float2 a0 = cfw[b], b0 = cfw[b + 4], c0 = cfw[b + 8], d0 = cfw[b + 12];
        float2 u0, u1, u2, u3;
        bfly4(a0, b0, c0, d0, u0, u1, u2, u3);
        float2 w1 = tw[16 * q];
        float2 w2 = cmul(w1, w1);
        float2 w3 = cmul(w2, w1);
        y0 = u0; y1 = cmul(u1, w1); y2 = cmul(u2, w2); y3 = cmul(u3, w3);
    }
    // ---- stage 4: quad shuffles
    float2 o0 = dft4_quad(y0, q);
    float2 o1 = dft4_quad(y1, q);
    float2 o2 = dft4_quad(y2, q);
    float2 o3 = dft4_quad(y3, q);

    const int k0 = lane >> 4, k1 = (lane >> 2) & 3;
    const int qm = ((q & 1) << 1) | (q >> 1);
    const int fbase = k0 + 4 * k1 + 64 * qm;

    // write Z at A3(x)=x+(x>>6)
    {
        const int f0 = fbase, f1 = fbase + 16, f2 = fbase + 32, f3 = fbase + 48;
        cfw[f0 + (f0 >> 6)] = o0;
        cfw[f1 + (f1 >> 6)] = o1;
        cfw[f2 + (f2 >> 6)] = o2;
        cfw[f3 + (f3 >> 6)] = o3;
    }

    float S = 0.f;
    float2 oz[4] = {o0, o1, o2, o3};
    #pragma unroll
    for (int k2 = 0; k2 < 4; ++k2) {
        const int f = fbase + 16 * k2;
        const int g = (256 - f) & 255;
        float2 A = oz[k2];
        float2 B = cfw[g + (g >> 6)];
        const float imAB = A.x * B.y + A.y * B.x;
        const float dmag = (B.x * B.x + B.y * B.y) - (A.x * A.x + A.y * A.y);
        S = fmaf(fr[k2].x, imAB, S);
        S = fmaf(fr[k2].y, dmag, S);
    }
    #pragma unroll
    for (int m = 32; m >= 1; m >>= 1) S += __shfl_xor(S, m);
    return S;
}

// Pre-DFT the rel table (digit-reversed lane order, norm + 1/256 + 1/2,1/4 folded in).
__global__ __launch_bounds__(256) void rel_fft_kernel(
    const float* __restrict__ rel, float2* __restrict__ FrP)
{
    __shared__ float rrow[256];
    const int tid = threadIdx.x;
    const int ri = blockIdx.x;
    const int lane = tid & 63;
    rrow[tid] = rel[ri * 256 + tid];
    __syncthreads();

    float rn2 = 0.f;
    #pragma unroll
    for (int j = 0; j < 4; ++j) { float v = rrow[lane + 64 * j]; rn2 = fmaf(v, v, rn2); }
    #pragma unroll
    for (int m = 32; m >= 1; m >>= 1) rn2 += __shfl_xor(rn2, m);
    const float scale = rsqrtf(fmaxf(rn2, 1e-12f)) * (1.0f / 256.0f);

    const int l = tid & 63, k2 = tid >> 6;
    const int q = l & 3;
    const int qm = ((q & 1) << 1) | (q >> 1);
    const int f = (l >> 4) + 4 * ((l >> 2) & 3) + 16 * k2 + 64 * qm;

    float ang = -PI2 * (float)f * (1.0f / 256.0f);
    float2 wstep = make_float2(__cosf(ang), __sinf(ang));
    float2 w = make_float2(1.f, 0.f);
    float re = 0.f, im = 0.f;
    #pragma unroll 4
    for (int k = 0; k < 256; ++k) {
        float rv = rrow[k];
        re = fmaf(rv, w.x, re);
        im = fmaf(rv, w.y, im);
        w = cmul(w, wstep);
    }
    FrP[ri * 256 + tid] = make_float2(re * (scale * 0.5f), im * (scale * 0.25f));
}

// Two scores per wave, software-pipelined: all global loads issued up front
// in use-order (z0, fr0, z1, fr1), so each wait drains only what's needed.
__global__ __launch_bounds__(256, 4) void score_kernel(
    const int* __restrict__ pos_h, const int* __restrict__ pos_t, const int* __restrict__ pos_r,
    const int* __restrict__ neg_h, const int* __restrict__ neg_t, const int* __restrict__ neg_r,
    const float* __restrict__ ent, const float2* __restrict__ FrP,
    float* __restrict__ scores)
{
    __shared__ float2 tw[256];
    __shared__ float2 cf[4][288];

    const int tid = threadIdx.x, wave = tid >> 6, lane = tid & 63;
    {
        float ang = -PI2 * (float)tid * (1.0f / 256.0f);
        tw[tid] = make_float2(__cosf(ang), __sinf(ang));
    }

    const int s0 = blockIdx.x * 8 + wave;
    const int s1 = s0 + 4;

    int hi0, ti0, ri0, hi1, ti1, ri1;
    if (s0 < BATCH) { hi0 = pos_h[s0]; ti0 = pos_t[s0]; ri0 = pos_r[s0]; }
    else { const int j = s0 - BATCH; hi0 = neg_h[j]; ti0 = neg_t[j]; ri0 = neg_r[j]; }
    if (s1 < BATCH) { hi1 = pos_h[s1]; ti1 = pos_t[s1]; ri1 = pos_r[s1]; }
    else { const int j = s1 - BATCH; hi1 = neg_h[j]; ti1 = neg_t[j]; ri1 = neg_r[j]; }

    const float* __restrict__ h0 = ent + (long)hi0 * HIDDEN;
    const float* __restrict__ t0 = ent + (long)ti0 * HIDDEN;
    const float* __restrict__ h1 = ent + (long)hi1 * HIDDEN;
    const float* __restrict__ t1 = ent + (long)ti1 * HIDDEN;
    const float2* __restrict__ fb0 = FrP + (long)ri0 * 256;
    const float2* __restrict__ fb1 = FrP + (long)ri1 * 256;

    float2 z0[4], z1[4], fr0[4], fr1[4];
    #pragma unroll
    for (int j = 0; j < 4; ++j) z0[j] = make_float2(h0[lane + 64 * j], t0[lane + 64 * j]);
    #pragma unroll
    for (int k2 = 0; k2 < 4; ++k2) fr0[k2] = fb0[k2 * 64 + lane];
    #pragma unroll
    for (int j = 0; j < 4; ++j) z1[j] = make_float2(h1[lane + 64 * j], t1[lane + 64 * j]);
    #pragma unroll
    for (int k2 = 0; k2 < 4; ++k2) fr1[k2] = fb1[k2 * 64 + lane];

    __syncthreads();
    float2* __restrict__ cfw = cf[wave];

    const float S0 = fft_contract(z0, fr0, cfw, tw, lane);
    if (lane == 0) scores[s0] = -1.0f / (1.0f + __expf(-S0));

    const float S1 = fft_contract(z1, fr1, cfw, tw, lane);
    if (lane == 0) scores[s1] = -1.0f / (1.0f + __expf(-S1));
}

// Deterministic single-block loss reduction (fully overwrites out[0]).
__global__ __launch_bounds__(1024) void loss_kernel(
    const float* __restrict__ scores, float* __restrict__ out)
{
    __shared__ float red[16];
    float sum = 0.f;
    for (int b = threadIdx.x; b < BATCH; b += 1024) {
        const float p = scores[b];
        const float* __restrict__ np = scores + BATCH + b * NEGS;
        float n = 0.f;
        #pragma unroll
        for (int j = 0; j < NEGS; ++j) n += np[j];
        n *= (1.0f / NEGS);
        sum += fmaxf(p - n + 1.0f, 0.0f);
    }
    #pragma unroll
    for (int m = 32; m >= 1; m >>= 1) sum += __shfl_xor(sum, m);
    const int wave = threadIdx.x >> 6;
    const int lane = threadIdx.x & 63;
    if (lane == 0) red[wave] = sum;
    __syncthreads();
    if (threadIdx.x < 16) {
        float v = red[threadIdx.x];
        #pragma unroll
        for (int m = 8; m >= 1; m >>= 1) v += __shfl_xor(v, m, 16);
        if (threadIdx.x == 0) out[0] = v;
    }
}

extern "C" void kernel_launch(void* const* d_in, const int* in_sizes, int n_in,
                              void* d_out, int out_size, void* d_ws, size_t ws_size,
                              hipStream_t stream) {
    (void)in_sizes; (void)n_in; (void)out_size; (void)ws_size;
    const int* pos_h = (const int*)d_in[0];
    const int* pos_t = (const int*)d_in[1];
    const int* pos_r = (const int*)d_in[2];
    const int* neg_h = (const int*)d_in[3];
    const int* neg_t = (const int*)d_in[4];
    const int* neg_r = (const int*)d_in[5];
    const float* ent = (const float*)d_in[6];
    const float* rel = (const float*)d_in[7];

    float2* FrP = (float2*)d_ws;                                    // 2,048,000 B
    float* scores = (float*)((char*)d_ws + 1000 * 256 * sizeof(float2));
    float* out = (float*)d_out;

    rel_fft_kernel<<<dim3(1000), dim3(256), 0, stream>>>(rel, FrP);
    score_kernel<<<dim3(NSCORES / 8), dim3(256), 0, stream>>>(
        pos_h, pos_t, pos_r, neg_h, neg_t, neg_r, ent, FrP, scores);
    loss_kernel<<<dim3(1), dim3(1024), 0, stream>>>(scores, out);
}

// Round 6
// 105.553 us; speedup vs baseline: 2.5266x; 1.0397x over previous
//
#include <hip/hip_runtime.h>
#include <math.h>

#define HIDDEN 256
#define BATCH 8192
#define NEGS 16
#define NSCORES (BATCH + BATCH * NEGS)  // 139264
#define PI2 6.28318530717958647692f

__device__ __forceinline__ float2 cmul(float2 a, float2 b) {
    return make_float2(fmaf(a.x, b.x, -a.y * b.y), fmaf(a.x, b.y, a.y * b.x));
}

// DIF radix-4 butterfly
__device__ __forceinline__ void bfly4(float2 a, float2 b, float2 c, float2 d,
                                      float2& u0, float2& u1, float2& u2, float2& u3) {
    float2 apc = make_float2(a.x + c.x, a.y + c.y);
    float2 amc = make_float2(a.x - c.x, a.y - c.y);
    float2 bpd = make_float2(b.x + d.x, b.y + d.y);
    float2 bmd = make_float2(b.x - d.x, b.y - d.y);
    u0 = make_float2(apc.x + bpd.x, apc.y + bpd.y);
    u2 = make_float2(apc.x - bpd.x, apc.y - bpd.y);
    u1 = make_float2(amc.x + bmd.y, amc.y - bmd.x);   // (a-c) - i(b-d)
    u3 = make_float2(amc.x - bmd.y, amc.y + bmd.x);   // (a-c) + i(b-d)
}

// Final DFT-4 across a quad of lanes via shfl_xor (quad_perm DPP);
// lane q ends with output digit qmap[q] = {0,2,1,3}.
__device__ __forceinline__ float2 dft4_quad(float2 y, int q) {
    float2 p = make_float2(__shfl_xor(y.x, 2), __shfl_xor(y.y, 2));
    float2 v;
    if (q & 2) { v.x = p.x - y.x; v.y = p.y - y.y; }
    else       { v.x = y.x + p.x; v.y = y.y + p.y; }
    if (q == 3) { float t = v.x; v.x = v.y; v.y = -t; }  // * -i
    float2 p2 = make_float2(__shfl_xor(v.x, 1), __shfl_xor(v.y, 1));
    float2 o;
    if (q & 1) { o.x = p2.x - v.x; o.y = p2.y - v.y; }
    else       { o.x = v.x + p2.x; o.y = v.y + p2.y; }
    return o;
}

// FFT-256 of z (element n = lane + 64*j) + contraction with preloaded fr[4].
// twa = W^lane, twb = W^{4*(lane&15)}, twc = W^{16*(lane&3)}, W = e^{-2pi i/256}.
// cfw is per-wave LDS scratch (288 float2); no cross-wave sharing.
__device__ __forceinline__ float fft_contract(const float2 z[4], const float2 fr[4],
                                              float2* __restrict__ cfw,
                                              float2 twa, float2 twb, float2 twc, int lane)
{
    // ---- stage 1 (N=256), in-lane over regs, write at A1(x)=x+(x>>6)
    {
        float2 u0, u1, u2, u3;
        bfly4(z[0], z[1], z[2], z[3], u0, u1, u2, u3);
        float2 w2 = cmul(twa, twa);
        float2 w3 = cmul(w2, twa);
        cfw[lane]       = u0;
        cfw[65 + lane]  = cmul(u1, twa);
        cfw[130 + lane] = cmul(u2, w2);
        cfw[195 + lane] = cmul(u3, w3);
    }
    // ---- stage 2 (N=64): lane = (s16, m); write at A2(x)=x+(x>>4)
    {
        const int s16 = lane >> 4, m = lane & 15;
        const int b = s16 * 65 + m;
        float2 a0 = cfw[b], b0 = cfw[b + 16], c0 = cfw[b + 32], d0 = cfw[b + 48];
        float2 u0, u1, u2, u3;
        bfly4(a0, b0, c0, d0, u0, u1, u2, u3);
        float2 w2 = cmul(twb, twb);
        float2 w3 = cmul(w2, twb);
        const int wb = s16 * 68 + m;
        cfw[wb]      = u0;
        cfw[wb + 17] = cmul(u1, twb);
        cfw[wb + 34] = cmul(u2, w2);
        cfw[wb + 51] = cmul(u3, w3);
    }
    // ---- stage 3 (N=16): lane = (sigma, q)
    float2 y0, y1, y2, y3;
    const int q = lane & 3;
    {
        const int sig = lane >> 2;
        const int b = sig * 17 + q;
        float2 a0 = cfw[b], b0 = cfw[b + 4], c0 = cfw[b + 8], d0 = cfw[b + 12];
        float2 u0, u1, u2, u3;
        bfly4(a0, b0, c0, d0, u0, u1, u2, u3);
        float2 w2 = cmul(twc, twc);
        float2 w3 = cmul(w2, twc);
        y0 = u0; y1 = cmul(u1, twc); y2 = cmul(u2, w2); y3 = cmul(u3, w3);
    }
    // ---- stage 4: quad shuffles (DPP)
    float2 o0 = dft4_quad(y0, q);
    float2 o1 = dft4_quad(y1, q);
    float2 o2 = dft4_quad(y2, q);
    float2 o3 = dft4_quad(y3, q);

    const int k0 = lane >> 4, k1 = (lane >> 2) & 3;
    const int qm = ((q & 1) << 1) | (q >> 1);
    const int fbase = k0 + 4 * k1 + 64 * qm;

    // write Z at A3(x)=x+(x>>6)
    {
        const int f0 = fbase, f1 = fbase + 16, f2 = fbase + 32, f3 = fbase + 48;
        cfw[f0 + (f0 >> 6)] = o0;
        cfw[f1 + (f1 >> 6)] = o1;
        cfw[f2 + (f2 >> 6)] = o2;
        cfw[f3 + (f3 >> 6)] = o3;
    }

    float S = 0.f;
    float2 oz[4] = {o0, o1, o2, o3};
    #pragma unroll
    for (int k2 = 0; k2 < 4; ++k2) {
        const int f = fbase + 16 * k2;
        const int g = (256 - f) & 255;
        float2 A = oz[k2];
        float2 B = cfw[g + (g >> 6)];
        const float imAB = A.x * B.y + A.y * B.x;
        const float dmag = (B.x * B.x + B.y * B.y) - (A.x * A.x + A.y * A.y);
        S = fmaf(fr[k2].x, imAB, S);
        S = fmaf(fr[k2].y, dmag, S);
    }
    #pragma unroll
    for (int m = 32; m >= 1; m >>= 1) S += __shfl_xor(S, m);
    return S;
}

// Pre-DFT the rel table (digit-reversed lane order; norm, 1/256, 1/2, 1/4 folded in).
// 4 interleaved twiddle chains for ILP.
__global__ __launch_bounds__(256) void rel_fft_kernel(
    const float* __restrict__ rel, float2* __restrict__ FrP)
{
    __shared__ float rrow[256];
    const int tid = threadIdx.x;
    const int ri = blockIdx.x;
    const int lane = tid & 63;
    rrow[tid] = rel[ri * 256 + tid];
    __syncthreads();

    float rn2 = 0.f;
    #pragma unroll
    for (int j = 0; j < 4; ++j) { float v = rrow[lane + 64 * j]; rn2 = fmaf(v, v, rn2); }
    #pragma unroll
    for (int m = 32; m >= 1; m >>= 1) rn2 += __shfl_xor(rn2, m);
    const float scale = rsqrtf(fmaxf(rn2, 1e-12f)) * (1.0f / 256.0f);

    const int l = tid & 63, k2 = tid >> 6;
    const int q = l & 3;
    const int qm = ((q & 1) << 1) | (q >> 1);
    const int f = (l >> 4) + 4 * ((l >> 2) & 3) + 16 * k2 + 64 * qm;

    float ang = -PI2 * (float)f * (1.0f / 256.0f);
    float2 ws = make_float2(__cosf(ang), __sinf(ang));
    float2 p = ws;
    #pragma unroll
    for (int u = 0; u < 6; ++u) p = cmul(p, p);    // ws^64
    float2 p2 = cmul(p, p);                        // ws^128
    float2 p3 = cmul(p2, p);                       // ws^192

    float2 w0 = make_float2(1.f, 0.f), w1 = p, w2 = p2, w3 = p3;
    float re0 = 0.f, im0 = 0.f, re1 = 0.f, im1 = 0.f;
    float re2 = 0.f, im2 = 0.f, re3 = 0.f, im3 = 0.f;
    #pragma unroll 4
    for (int k = 0; k < 64; ++k) {
        float v0 = rrow[k], v1 = rrow[k + 64], v2 = rrow[k + 128], v3 = rrow[k + 192];
        re0 = fmaf(v0, w0.x, re0); im0 = fmaf(v0, w0.y, im0);
        re1 = fmaf(v1, w1.x, re1); im1 = fmaf(v1, w1.y, im1);
        re2 = fmaf(v2, w2.x, re2); im2 = fmaf(v2, w2.y, im2);
        re3 = fmaf(v3, w3.x, re3); im3 = fmaf(v3, w3.y, im3);
        w0 = cmul(w0, ws); w1 = cmul(w1, ws); w2 = cmul(w2, ws); w3 = cmul(w3, ws);
    }
    const float re = (re0 + re1) + (re2 + re3);
    const float im = (im0 + im1) + (im2 + im3);
    FrP[ri * 256 + tid] = make_float2(re * (scale * 0.5f), im * (scale * 0.25f));
}

// One score per wave; no barriers; target <=64 VGPR for 8 waves/SIMD.
__global__ __launch_bounds__(256, 8) void score_kernel(
    const int* __restrict__ pos_h, const int* __restrict__ pos_t, const int* __restrict__ pos_r,
    const int* __restrict__ neg_h, const int* __restrict__ neg_t, const int* __restrict__ neg_r,
    const float* __restrict__ ent, const float2* __restrict__ FrP,
    float* __restrict__ scores)
{
    __shared__ float2 cf[4][288];
    const int tid = threadIdx.x, wave = tid >> 6, lane = tid & 63;
    const int s = blockIdx.x * 4 + wave;

    const bool isp = s < BATCH;
    const int j = isp ? s : s - BATCH;
    const int hi = (isp ? pos_h : neg_h)[j];
    const int ti = (isp ? pos_t : neg_t)[j];
    const int ri = (isp ? pos_r : neg_r)[j];

    const float* __restrict__ hrow = ent + (long)hi * HIDDEN;
    const float* __restrict__ trow = ent + (long)ti * HIDDEN;
    const float2* __restrict__ fb = FrP + (long)ri * 256;

    float2 z[4], fr[4];
    #pragma unroll
    for (int u = 0; u < 4; ++u)
        z[u] = make_float2(hrow[lane + 64 * u], trow[lane + 64 * u]);
    #pragma unroll
    for (int u = 0; u < 4; ++u) fr[u] = fb[u * 64 + lane];

    const float a1 = -PI2 * (1.0f / 256.0f) * (float)lane;
    const float a2 = -PI2 * (1.0f / 256.0f) * (float)(4 * (lane & 15));
    const float a3 = -PI2 * (1.0f / 256.0f) * (float)(16 * (lane & 3));
    const float2 twa = make_float2(__cosf(a1), __sinf(a1));
    const float2 twb = make_float2(__cosf(a2), __sinf(a2));
    const float2 twc = make_float2(__cosf(a3), __sinf(a3));

    const float S = fft_contract(z, fr, cf[wave], twa, twb, twc, lane);
    if (lane == 0) scores[s] = -1.0f / (1.0f + __expf(-S));
}

// Deterministic single-block loss reduction (fully overwrites out[0]).
__global__ __launch_bounds__(1024) void loss_kernel(
    const float* __restrict__ scores, float* __restrict__ out)
{
    __shared__ float red[16];
    float sum = 0.f;
    for (int b = threadIdx.x; b < BATCH; b += 1024) {
        const float p = scores[b];
        const float* __restrict__ np = scores + BATCH + b * NEGS;
        float n = 0.f;
        #pragma unroll
        for (int j = 0; j < NEGS; ++j) n += np[j];
        n *= (1.0f / NEGS);
        sum += fmaxf(p - n + 1.0f, 0.0f);
    }
    #pragma unroll
    for (int m = 32; m >= 1; m >>= 1) sum += __shfl_xor(sum, m);
    const int wave = threadIdx.x >> 6;
    const int lane = threadIdx.x & 63;
    if (lane == 0) red[wave] = sum;
    __syncthreads();
    if (threadIdx.x < 16) {
        float v = red[threadIdx.x];
        #pragma unroll
        for (int m = 8; m >= 1; m >>= 1) v += __shfl_xor(v, m, 16);
        if (threadIdx.x == 0) out[0] = v;
    }
}

extern "C" void kernel_launch(void* const* d_in, const int* in_sizes, int n_in,
                              void* d_out, int out_size, void* d_ws, size_t ws_size,
                              hipStream_t stream) {
    (void)in_sizes; (void)n_in; (void)out_size; (void)ws_size;
    const int* pos_h = (const int*)d_in[0];
    const int* pos_t = (const int*)d_in[1];
    const int* pos_r = (const int*)d_in[2];
    const int* neg_h = (const int*)d_in[3];
    const int* neg_t = (const int*)d_in[4];
    const int* neg_r = (const int*)d_in[5];
    const float* ent = (const float*)d_in[6];
    const float* rel = (const float*)d_in[7];

    float2* FrP = (float2*)d_ws;                                    // 2,048,000 B
    float* scores = (float*)((char*)d_ws + 1000 * 256 * sizeof(float2));
    float* out = (float*)d_out;

    rel_fft_kernel<<<dim3(1000), dim3(256), 0, stream>>>(rel, FrP);
    score_kernel<<<dim3(NSCORES / 4), dim3(256), 0, stream>>>(
        pos_h, pos_t, pos_r, neg_h, neg_t, neg_r, ent, FrP, scores);
    loss_kernel<<<dim3(1), dim3(1024), 0, stream>>>(scores, out);
}